// Round 16
// baseline (501.718 us; speedup 1.0000x reference)
//
#include <hip/hip_runtime.h>
#include <stdint.h>

#define NB 64
#define NL 20
#define ND 2304
#define NE 4
#define NH 4608
#define NM 1280   // B*L

typedef float f32x4 __attribute__((ext_vector_type(4)));
typedef __bf16 bf16x8 __attribute__((ext_vector_type(8)));
typedef unsigned short u16;
typedef u16 u16x4 __attribute__((ext_vector_type(4)));
typedef unsigned int u32;
typedef u32 u32x4 __attribute__((ext_vector_type(4)));

__device__ __forceinline__ u16 f2bf(float f) {
  u32 u = __builtin_bit_cast(u32, f);
  u += 0x7fffu + ((u >> 16) & 1u);
  return (u16)(u >> 16);
}

// async global->LDS, 16 B per lane; dest is wave-uniform base + lane*16
__device__ __forceinline__ void gl_lds16(const void* g, void* l) {
  __builtin_amdgcn_global_load_lds(
      (const __attribute__((address_space(1))) void*)g,
      (__attribute__((address_space(3))) void*)l, 16, 0, 0);
}

// ---- ws layout (float offsets) ----
#define OFF_XF    147456
#define OFF_H     294912     // Hb bf16 [192][4608]
#define OFF_Y     1179648    // [192][2304] f32
#define OFF_AUX   1622016
#define OFF_CNT   1622020
#define OFF_ROWS  1622032
#define OFF_OFB   1622240
#define OFF_H1B   3096800
#define OFF_ENCWB 4571360
#define OFF_DECWB 7225568
#define OFF_XC    9879776    // Xcb bf16 [192][2304]
#define OFF_P     10322144   // partial buffer: 7077888 f32 (also conv partials)

// Fused conv1(3x3x3,pad1,relu) + conv2 d-slice partial, 16-row y-strips.
__global__ __launch_bounds__(256) void k_conv(
    const float* __restrict__ in, const float* __restrict__ w1,
    const float* __restrict__ b1, const float* __restrict__ w2,
    float* __restrict__ xfp) {
  __shared__ float insl[3][20][50];
  __shared__ float c1[2][18][50];
  __shared__ float w1s[270];
  __shared__ float w2s[90];
  __shared__ float b1s[10];
  const int d = blockIdx.x, b = blockIdx.y, h = blockIdx.z, t = threadIdx.x;
  const int gy0 = h * 16;
  for (int i = t; i < 270; i += 256) w1s[i] = w1[i];
  for (int i = t; i < 90; i += 256) w2s[i] = w2[(size_t)((i / 9) * 20 + d) * 9 + (i % 9)];
  if (t < 10) b1s[t] = b1[t];
  for (int i = t; i < 3000; i += 256) {
    int s = i / 1000, rr = (i % 1000) / 50, cc = i % 50;
    int gd = d - 1 + s, gy = gy0 - 2 + rr, gx = cc - 1;
    float v = 0.f;
    if (gd >= 0 && gd < NL && (unsigned)gy < 48u && (unsigned)gx < 48u)
      v = in[((size_t)b * NL + gd) * ND + gy * 48 + gx];
    insl[s][rr][cc] = v;
  }
  for (int i = t; i < 1800; i += 256) ((float*)c1)[i] = 0.f;
  float s2[4] = {0.f, 0.f, 0.f, 0.f};
  const int y1 = t / 12, x0 = (t % 12) * 4;
  __syncthreads();
  for (int pc = 0; pc < 5; ++pc) {
    if (t < 216) {
      const int gr = gy0 - 1 + y1;
      if ((unsigned)gr < 48u) {
        float a0[4], a1[4];
        const float bb0 = b1s[2 * pc], bb1 = b1s[2 * pc + 1];
#pragma unroll
        for (int xq = 0; xq < 4; ++xq) { a0[xq] = bb0; a1[xq] = bb1; }
#pragma unroll
        for (int kd = 0; kd < 3; ++kd)
#pragma unroll
          for (int ky = 0; ky < 3; ++ky) {
            float v[6];
#pragma unroll
            for (int i = 0; i < 6; ++i) v[i] = insl[kd][y1 + ky][x0 + i];
            const float* wa = &w1s[(2 * pc) * 27 + kd * 9 + ky * 3];
            const float* wb = wa + 27;
#pragma unroll
            for (int xq = 0; xq < 4; ++xq) {
              a0[xq] += v[xq] * wa[0] + v[xq + 1] * wa[1] + v[xq + 2] * wa[2];
              a1[xq] += v[xq] * wb[0] + v[xq + 1] * wb[1] + v[xq + 2] * wb[2];
            }
          }
#pragma unroll
        for (int xq = 0; xq < 4; ++xq) {
          c1[0][y1][x0 + 1 + xq] = fmaxf(a0[xq], 0.f);
          c1[1][y1][x0 + 1 + xq] = fmaxf(a1[xq], 0.f);
        }
      }
    }
    __syncthreads();
    if (t < 192) {
#pragma unroll
      for (int cc = 0; cc < 2; ++cc) {
#pragma unroll
        for (int ky = 0; ky < 3; ++ky) {
          float v[6];
#pragma unroll
          for (int i = 0; i < 6; ++i) v[i] = c1[cc][y1 + ky][x0 + i];
          const float* wr = &w2s[(2 * pc + cc) * 9 + ky * 3];
#pragma unroll
          for (int xq = 0; xq < 4; ++xq)
            s2[xq] += v[xq] * wr[0] + v[xq + 1] * wr[1] + v[xq + 2] * wr[2];
        }
      }
    }
    __syncthreads();
  }
  if (t < 192) {
    f32x4 o = {s2[0], s2[1], s2[2], s2[3]};
    *(f32x4*)(xfp + ((size_t)d * NB + b) * ND + (gy0 + y1) * 48 + x0) = o;
  }
}

// Reduce conv partials over d + bias + relu.
__global__ __launch_bounds__(256) void k_bias_relu(
    const float* __restrict__ xfp, const float* __restrict__ c2b, float* __restrict__ xf) {
  const size_t i = (size_t)blockIdx.x * 256 + threadIdx.x;
  float s = c2b[0];
#pragma unroll
  for (int d = 0; d < NL; ++d) s += xfp[(size_t)d * (NB * ND) + i];
  xf[i] = fmaxf(s, 0.f);
}

// Gating: logits, argmax (top-1, gate=1.0), counts, row compaction, aux loss.
__global__ __launch_bounds__(256) void k_gate(
    const float* __restrict__ xf,
    const float* __restrict__ g0, const float* __restrict__ g1, const float* __restrict__ g2,
    float* __restrict__ aux, int* __restrict__ cnt, int* __restrict__ rows) {
  const int p = blockIdx.x, t = threadIdx.x;
  const float* __restrict__ g = (p == 0) ? g0 : ((p == 1) ? g1 : g2);
  __shared__ float lg[64][4];
  __shared__ int lidx[64];
  __shared__ int lcnt[4];
  if (t < 4) lcnt[t] = 0;
  const int wv = t >> 6, l = t & 63;
  for (int b0 = 0; b0 < 64; b0 += 4) {
    int bb = b0 + wv;
    f32x4 acc = {0.f, 0.f, 0.f, 0.f};
    const float* xr = xf + (size_t)bb * ND + l * 36;
    const float* gr = g + (size_t)l * 36 * 4;
#pragma unroll
    for (int i4 = 0; i4 < 9; ++i4) {
      f32x4 xv = *(const f32x4*)(xr + i4 * 4);
#pragma unroll
      for (int qq = 0; qq < 4; ++qq) {
        f32x4 gv = *(const f32x4*)(gr + (i4 * 4 + qq) * 4);
        acc += xv[qq] * gv;
      }
    }
#pragma unroll
    for (int e = 0; e < 4; ++e) {
      float pv = acc[e];
#pragma unroll
      for (int off = 32; off > 0; off >>= 1) pv += __shfl_down(pv, off);
      if (l == 0) lg[bb][e] = pv;
    }
  }
  __syncthreads();
  if (t < 64) {
    float best = lg[t][0];
    int bi = 0;
#pragma unroll
    for (int e = 1; e < 4; ++e)
      if (lg[t][e] > best) { best = lg[t][e]; bi = e; }
    lidx[t] = bi;
    atomicAdd(&lcnt[bi], 1);
  }
  __syncthreads();
  if (t == 0) {
    int ofs[4]; int run = 0;
#pragma unroll
    for (int e = 0; e < 4; ++e) { ofs[e] = run; run += lcnt[e]; cnt[p * 4 + e] = lcnt[e]; }
    for (int b = 0; b < 64; ++b) { int e = lidx[b]; rows[p * 64 + ofs[e]++] = b; }
    float var = 0.f;
#pragma unroll
    for (int e = 0; e < 4; ++e) { float dd = (float)lcnt[e] - 16.f; var += dd * dd; }
    var *= (1.f / 3.f);
    aux[p] = 0.02f * var / (256.f + 1e-10f);
  }
}

// Compact xf rows into expert order + fp32->bf16: Xb[slot] = bf16(xf[rows[slot]]).
__global__ __launch_bounds__(256) void k_gather(
    const float* __restrict__ xf, const int* __restrict__ rows, u16* __restrict__ Xb) {
  const int slot = blockIdx.x, t = threadIdx.x;
  const int r = rows[slot];
  const f32x4* src = (const f32x4*)(xf + (size_t)r * ND);
  u16x4* dst = (u16x4*)(Xb + (size_t)slot * ND);
  for (int i = t; i < ND / 4; i += 256) {
    f32x4 v = src[i];
    u16x4 o;
#pragma unroll
    for (int q = 0; q < 4; ++q) o[q] = f2bf(v[q]);
    dst[i] = o;
  }
}

// MFMA expert GEMM v6 (frozen): 256-col weight tiles, 1KB contiguous staging,
// ring-2 LDS, counted vmcnt. 16 rows x 256 cols x KL=288 per block.
template <int K, int N, int KS>
__global__ __launch_bounds__(256) void k_moe_mfma(
    const u16* __restrict__ Xb,
    const float* __restrict__ wt, const float* __restrict__ wa, const float* __restrict__ wq,
    const int* __restrict__ cnt, float* __restrict__ P) {
  constexpr int KL = K / KS;      // 288
  constexpr int NT = KL / 32;     // 9
  const int tile = blockIdx.x;    // 256-col tile
  const int ks = blockIdx.y;
  const int pe = blockIdx.z >> 2, ch = blockIdx.z & 3;
  const int p = pe >> 2, e = pe & 3;
  const int c = cnt[p * 4 + e];
  const int rstart = ch * 16;
  if (rstart >= c) return;
  const int nrows = min(16, c - rstart);
  int pref = 0;
  for (int e2 = 0; e2 < e; ++e2) pref += cnt[p * 4 + e2];
  const int slot0 = p * 64 + pref + rstart;
  const float* __restrict__ W = (p == 0) ? wt : ((p == 1) ? wa : wq);
  __shared__ float wb[2][32 * 260 + 24];   // rows at k*260 + ((k>>3)&3)*8
  const int t = threadIdx.x;
  const int w = t >> 6, l = t & 63;
  const int l15 = l & 15, l4 = l >> 4;

  int ar = slot0 + l15; if (ar > 191) ar = 191;
  const u16* Ag = Xb + (size_t)ar * K + ks * KL + l4 * 8;
  bf16x8 areg[NT];
#pragma unroll
  for (int kt = 0; kt < NT; ++kt) areg[kt] = *(const bf16x8*)(Ag + kt * 32);

  const float* Wg = W + (size_t)e * K * N + (size_t)(ks * KL) * N + tile * 256;
#define STAGE(BUF, KT)                                                        \
  { _Pragma("unroll")                                                         \
    for (int j = 0; j < 8; ++j)                                               \
      gl_lds16(Wg + (size_t)((KT) * 32 + w * 8 + j) * N + l * 4,              \
               &wb[BUF][(w * 8 + j) * 260 + w * 8]); }

  f32x4 acc[4] = {};

#define CONSUME(KT)                                                           \
  { const float* ww = &wb[(KT) & 1][0];                                       \
    const int kb = l4 * 8 * 260 + l4 * 8 + w * 64 + l15;                      \
    _Pragma("unroll")                                                         \
    for (int i = 0; i < 4; ++i) {                                             \
      bf16x8 bfr;                                                             \
      _Pragma("unroll")                                                       \
      for (int j = 0; j < 8; ++j) bfr[j] = (__bf16)ww[kb + j * 260 + i * 16]; \
      acc[i] = __builtin_amdgcn_mfma_f32_16x16x32_bf16(areg[KT], bfr, acc[i], 0, 0, 0); \
    } }

  STAGE(0, 0);
  STAGE(1, 1);
#pragma unroll
  for (int kt = 0; kt < NT; ++kt) {
    if (kt < NT - 1) { asm volatile("s_waitcnt vmcnt(8)" ::: "memory"); }
    else             { asm volatile("s_waitcnt vmcnt(0)" ::: "memory"); }
    __syncthreads();
    CONSUME(kt);
    __syncthreads();
    if (kt + 2 < NT) STAGE(kt & 1, kt + 2);
  }
#undef STAGE
#undef CONSUME

  const size_t pbase = (size_t)ks * 192 * N;
#pragma unroll
  for (int i = 0; i < 4; ++i) {
    const int n = tile * 256 + w * 64 + i * 16 + l15;
#pragma unroll
    for (int r = 0; r < 4; ++r) {
      const int m = l4 * 4 + r;
      if (m < nrows) P[pbase + (size_t)(slot0 + m) * N + n] = acc[i][r];
    }
  }
}

// Reduce phase-A partials: Hb[slot][j] = bf16(relu(sum_ks P + b1[e])).
__global__ __launch_bounds__(256) void k_red1(
    const float* __restrict__ P,
    const float* __restrict__ b1t, const float* __restrict__ b1a, const float* __restrict__ b1q,
    const int* __restrict__ cnt, u16* __restrict__ Hb) {
  const int slot = blockIdx.y;
  const int p = slot >> 6, pos = slot & 63;
  int e = 0, run = cnt[p * 4];
  while (pos >= run && e < 3) { ++e; run += cnt[p * 4 + e]; }
  const float* __restrict__ b1 = (p == 0) ? b1t : ((p == 1) ? b1a : b1q);
  const int j0 = blockIdx.x * 1024 + threadIdx.x * 4;
  if (j0 >= NH) return;
  f32x4 s = *(const f32x4*)(b1 + (size_t)e * NH + j0);
#pragma unroll
  for (int ks = 0; ks < 8; ++ks)
    s += *(const f32x4*)(P + ((size_t)ks * 192 + slot) * NH + j0);
  u16x4 o;
#pragma unroll
  for (int q = 0; q < 4; ++q) o[q] = f2bf(fmaxf(s[q], 0.f));
  *(u16x4*)(Hb + (size_t)slot * NH + j0) = o;
}

// Reduce phase-B partials + scatter: Y[p*64+rows[slot]][j] = sum_ks P + b2[e].
__global__ __launch_bounds__(256) void k_red2(
    const float* __restrict__ P,
    const float* __restrict__ b2t, const float* __restrict__ b2a, const float* __restrict__ b2q,
    const int* __restrict__ cnt, const int* __restrict__ rows, float* __restrict__ Y) {
  const int slot = blockIdx.y;
  const int p = slot >> 6, pos = slot & 63;
  int e = 0, run = cnt[p * 4];
  while (pos >= run && e < 3) { ++e; run += cnt[p * 4 + e]; }
  const float* __restrict__ b2 = (p == 0) ? b2t : ((p == 1) ? b2a : b2q);
  const int b = rows[slot];
  const int t = threadIdx.x;
  if (t >= 192) return;
  const int j0 = blockIdx.x * 768 + t * 4;
  f32x4 s = *(const f32x4*)(b2 + (size_t)e * ND + j0);
#pragma unroll
  for (int ks = 0; ks < 16; ++ks)
    s += *(const f32x4*)(P + ((size_t)ks * 192 + slot) * ND + j0);
  *(f32x4*)(Y + (size_t)(p * 64 + b) * ND + j0) = s;
}

// out = in*in*quad + in*transform + add, convert to bf16 for encoder GEMM.
__global__ __launch_bounds__(256) void k_combine(
    const float* __restrict__ in, const float* __restrict__ Y, u16* __restrict__ ofb) {
  const size_t i = (size_t)blockIdx.x * 256 + threadIdx.x;
  const size_t e0 = i * 4;
  const int row = (int)(e0 / ND);
  const int d = (int)(e0 - (size_t)row * ND);
  const int b = row / NL;
  f32x4 v = *(const f32x4*)(in + e0);
  const size_t yb = (size_t)b * ND + d;
  f32x4 tt = *(const f32x4*)(Y + yb);
  f32x4 aa = *(const f32x4*)(Y + (size_t)64 * ND + yb);
  f32x4 qq = *(const f32x4*)(Y + (size_t)128 * ND + yb);
  u16x4 o;
#pragma unroll
  for (int q = 0; q < 4; ++q) {
    float f = v[q] * v[q] * qq[q] + v[q] * tt[q] + aa[q];
    o[q] = f2bf(f);
  }
  *(u16x4*)(ofb + e0) = o;
}

// Transpose + fp32->bf16, 4 k-tiles per block: W^T so GEMM B is [N][K].
__global__ __launch_bounds__(256) void k_wt(
    const float* __restrict__ encw, const float* __restrict__ decw,
    u16* __restrict__ encb, u16* __restrict__ decb) {
  __shared__ float tl[32][33];
  const float* __restrict__ src = blockIdx.z ? decw : encw;
  u16* __restrict__ dst = blockIdx.z ? decb : encb;
  const int n0 = blockIdx.y * 32;
  const int tx = threadIdx.x & 31, ty = threadIdx.x >> 5;
#pragma unroll 1
  for (int s = 0; s < 4; ++s) {
    const int k0 = blockIdx.x * 128 + s * 32;
    for (int r = ty; r < 32; r += 8) tl[r][tx] = src[(size_t)(k0 + r) * ND + n0 + tx];
    __syncthreads();
    for (int r = ty; r < 32; r += 8) dst[(size_t)(n0 + r) * ND + k0 + tx] = f2bf(tl[tx][r]);
    __syncthreads();
  }
}

// 32x128 bf16 MFMA GEMM (720 blocks), A[M][K] row-major, Bt[N][K] row-major.
template <int MODE>
__global__ __launch_bounds__(256) void k_gemm(
    const u16* __restrict__ A, const u16* __restrict__ Bt,
    const float* __restrict__ bias, void* __restrict__ outp,
    const float* __restrict__ aux) {
  __shared__ u16 As[32 * 32];
  __shared__ u16 Bs[128 * 32];
  const int t = threadIdx.x;
  const int bm = blockIdx.x, bn = blockIdx.y;
  const int lane = t & 63;
  const int wr = (t >> 7) & 1, wc = (t >> 6) & 1;
  const int l15 = lane & 15, l4 = lane >> 4;
  f32x4 acc[4] = {};
  const int r0 = t >> 2, kc0 = (t & 3) * 8;
  const int r1 = (t + 256) >> 2;
  const size_t baseA = (size_t)(bm * 32) * ND;
  const size_t baseB = (size_t)(bn * 128) * ND;
  for (int k0 = 0; k0 < ND; k0 += 32) {
    if (t < 128)
      *(u32x4*)(As + t * 8) = *(const u32x4*)(A + baseA + (size_t)(t >> 2) * ND + k0 + kc0);
    *(u32x4*)(Bs + t * 8) = *(const u32x4*)(Bt + baseB + (size_t)r0 * ND + k0 + kc0);
    *(u32x4*)(Bs + (t + 256) * 8) = *(const u32x4*)(Bt + baseB + (size_t)r1 * ND + k0 + kc0);
    __syncthreads();
    bf16x8 af, bfr[4];
    af = *(const bf16x8*)(As + (wr * 16 + l15) * 32 + l4 * 8);
#pragma unroll
    for (int i = 0; i < 4; ++i)
      bfr[i] = *(const bf16x8*)(Bs + (wc * 64 + i * 16 + l15) * 32 + l4 * 8);
#pragma unroll
    for (int ni = 0; ni < 4; ++ni)
      acc[ni] = __builtin_amdgcn_mfma_f32_16x16x32_bf16(af, bfr[ni], acc[ni], 0, 0, 0);
    __syncthreads();
  }
  const int colbase = bn * 128 + wc * 64;
  const int rowbase = bm * 32 + wr * 16;
#pragma unroll
  for (int ni = 0; ni < 4; ++ni) {
    const int colg = colbase + ni * 16 + l15;
    const float bv = bias[colg];
#pragma unroll
    for (int r = 0; r < 4; ++r) {
      const int rowg = rowbase + l4 * 4 + r;
      float v = acc[ni][r] + bv;
      if (MODE == 0) {
        ((u16*)outp)[(size_t)rowg * ND + colg] = f2bf(fmaxf(v, 0.f));
      } else {
        ((float*)outp)[(size_t)rowg * ND + colg] = 1.f / (1.f + __expf(-v));
      }
    }
  }
  if (MODE == 1 && bm == 0 && bn == 0 && t == 0)
    ((float*)outp)[(size_t)NM * ND] = aux[0] + aux[1] + aux[2];
}

extern "C" void kernel_launch(void* const* d_in, const int* in_sizes, int n_in,
                              void* d_out, int out_size, void* d_ws, size_t ws_size,
                              hipStream_t stream) {
  (void)in_sizes; (void)n_in; (void)out_size; (void)ws_size;
  const float* input   = (const float*)d_in[0];
  const float* conv1_w = (const float*)d_in[1];
  const float* conv1_b = (const float*)d_in[2];
  const float* conv2_w = (const float*)d_in[3];
  const float* conv2_b = (const float*)d_in[4];
  const float* enc_w   = (const float*)d_in[5];
  const float* enc_b   = (const float*)d_in[6];
  const float* dec_w   = (const float*)d_in[7];
  const float* dec_b   = (const float*)d_in[8];
  const float* gate_t = (const float*)d_in[9];
  const float* w1_t   = (const float*)d_in[10];
  const float* b1_t   = (const float*)d_in[11];
  const float* w2_t   = (const float*)d_in[12];
  const float* b2_t   = (const float*)d_in[13];
  const float* gate_a = (const float*)d_in[14];
  const float* w1_a   = (const float*)d_in[15];
  const float* b1_a   = (const float*)d_in[16];
  const float* w2_a   = (const float*)d_in[17];
  const float* b2_a   = (const float*)d_in[18];
  const float* gate_q = (const float*)d_in[19];
  const float* w1_q   = (const float*)d_in[20];
  const float* b1_q   = (const float*)d_in[21];
  const float* w2_q   = (const float*)d_in[22];
  const float* b2_q   = (const float*)d_in[23];

  float* ws = (float*)d_ws;
  float* xf     = ws + OFF_XF;
  u16*   Hb     = (u16*)(ws + OFF_H);
  float* Y      = ws + OFF_Y;
  float* aux    = ws + OFF_AUX;
  int*   cnt    = (int*)(ws + OFF_CNT);
  int*   rows   = (int*)(ws + OFF_ROWS);
  u16*   ofb    = (u16*)(ws + OFF_OFB);
  u16*   h1b    = (u16*)(ws + OFF_H1B);
  u16*   encwb  = (u16*)(ws + OFF_ENCWB);
  u16*   decwb  = (u16*)(ws + OFF_DECWB);
  u16*   Xcb    = (u16*)(ws + OFF_XC);
  float* P      = ws + OFF_P;

  // conv partials live in P-space (consumed by k_bias_relu before MoE writes P)
  k_conv<<<dim3(20, 64, 3), 256, 0, stream>>>(input, conv1_w, conv1_b, conv2_w, P);
  k_bias_relu<<<576, 256, 0, stream>>>(P, conv2_b, xf);
  k_wt<<<dim3(18, 72, 2), 256, 0, stream>>>(enc_w, dec_w, encwb, decwb);
  k_gate<<<3, 256, 0, stream>>>(xf, gate_t, gate_a, gate_q, aux, cnt, rows);
  k_gather<<<192, 256, 0, stream>>>(xf, rows, Xcb);
  // Phase A: Xcb(bf16, A-in-regs) @ w1(fp32, 1KB-chunk staging) -> P -> Hb(bf16)
  k_moe_mfma<ND, NH, 8><<<dim3(18, 8, 48), 256, 0, stream>>>(Xcb, w1_t, w1_a, w1_q, cnt, P);
  k_red1<<<dim3(5, 192), 256, 0, stream>>>(P, b1_t, b1_a, b1_q, cnt, Hb);
  // Phase B: Hb(bf16) @ w2 -> P -> Y (scattered, fp32)
  k_moe_mfma<NH, ND, 16><<<dim3(9, 16, 48), 256, 0, stream>>>(Hb, w2_t, w2_a, w2_q, cnt, P);
  k_red2<<<dim3(3, 192), 256, 0, stream>>>(P, b2_t, b2_a, b2_q, cnt, rows, Y);
  k_combine<<<2880, 256, 0, stream>>>(input, Y, ofb);
  k_gemm<0><<<dim3(40, 18), 256, 0, stream>>>(ofb, encwb, enc_b, (void*)h1b, aux);
  k_gemm<1><<<dim3(40, 18), 256, 0, stream>>>(h1b, decwb, dec_b, d_out, aux);
}

// Round 17
// 481.313 us; speedup vs baseline: 1.0424x; 1.0424x over previous
//
#include <hip/hip_runtime.h>
#include <stdint.h>

#define NB 64
#define NL 20
#define ND 2304
#define NE 4
#define NH 4608
#define NM 1280   // B*L

typedef float f32x4 __attribute__((ext_vector_type(4)));
typedef __bf16 bf16x8 __attribute__((ext_vector_type(8)));
typedef unsigned short u16;
typedef u16 u16x4 __attribute__((ext_vector_type(4)));
typedef unsigned int u32;
typedef u32 u32x4 __attribute__((ext_vector_type(4)));

__device__ __forceinline__ u16 f2bf(float f) {
  u32 u = __builtin_bit_cast(u32, f);
  u += 0x7fffu + ((u >> 16) & 1u);
  return (u16)(u >> 16);
}

// async global->LDS, 16 B per lane; dest is wave-uniform base + lane*16
__device__ __forceinline__ void gl_lds16(const void* g, void* l) {
  __builtin_amdgcn_global_load_lds(
      (const __attribute__((address_space(1))) void*)g,
      (__attribute__((address_space(3))) void*)l, 16, 0, 0);
}

// ---- ws layout (float offsets) ----
#define OFF_XF    147456
#define OFF_H     294912     // Hb bf16 [192][4608]
#define OFF_Y     1179648    // [192][2304] f32
#define OFF_AUX   1622016
#define OFF_CNT   1622020
#define OFF_ROWS  1622032
#define OFF_OFB   1622240
#define OFF_H1B   3096800
#define OFF_ENCWB 4571360
#define OFF_DECWB 7225568
#define OFF_XC    9879776    // Xcb bf16 [192][2304]
#define OFF_P     10322144   // partial buffer: 7077888 f32 (also conv partials)

// Fused conv1(3x3x3,pad1,relu) + conv2 d-slice partial, 16-row y-strips.
__global__ __launch_bounds__(256) void k_conv(
    const float* __restrict__ in, const float* __restrict__ w1,
    const float* __restrict__ b1, const float* __restrict__ w2,
    float* __restrict__ xfp) {
  __shared__ float insl[3][20][50];
  __shared__ float c1[2][18][50];
  __shared__ float w1s[270];
  __shared__ float w2s[90];
  __shared__ float b1s[10];
  const int d = blockIdx.x, b = blockIdx.y, h = blockIdx.z, t = threadIdx.x;
  const int gy0 = h * 16;
  for (int i = t; i < 270; i += 256) w1s[i] = w1[i];
  for (int i = t; i < 90; i += 256) w2s[i] = w2[(size_t)((i / 9) * 20 + d) * 9 + (i % 9)];
  if (t < 10) b1s[t] = b1[t];
  for (int i = t; i < 3000; i += 256) {
    int s = i / 1000, rr = (i % 1000) / 50, cc = i % 50;
    int gd = d - 1 + s, gy = gy0 - 2 + rr, gx = cc - 1;
    float v = 0.f;
    if (gd >= 0 && gd < NL && (unsigned)gy < 48u && (unsigned)gx < 48u)
      v = in[((size_t)b * NL + gd) * ND + gy * 48 + gx];
    insl[s][rr][cc] = v;
  }
  for (int i = t; i < 1800; i += 256) ((float*)c1)[i] = 0.f;
  float s2[4] = {0.f, 0.f, 0.f, 0.f};
  const int y1 = t / 12, x0 = (t % 12) * 4;
  __syncthreads();
  for (int pc = 0; pc < 5; ++pc) {
    if (t < 216) {
      const int gr = gy0 - 1 + y1;
      if ((unsigned)gr < 48u) {
        float a0[4], a1[4];
        const float bb0 = b1s[2 * pc], bb1 = b1s[2 * pc + 1];
#pragma unroll
        for (int xq = 0; xq < 4; ++xq) { a0[xq] = bb0; a1[xq] = bb1; }
#pragma unroll
        for (int kd = 0; kd < 3; ++kd)
#pragma unroll
          for (int ky = 0; ky < 3; ++ky) {
            float v[6];
#pragma unroll
            for (int i = 0; i < 6; ++i) v[i] = insl[kd][y1 + ky][x0 + i];
            const float* wa = &w1s[(2 * pc) * 27 + kd * 9 + ky * 3];
            const float* wb = wa + 27;
#pragma unroll
            for (int xq = 0; xq < 4; ++xq) {
              a0[xq] += v[xq] * wa[0] + v[xq + 1] * wa[1] + v[xq + 2] * wa[2];
              a1[xq] += v[xq] * wb[0] + v[xq + 1] * wb[1] + v[xq + 2] * wb[2];
            }
          }
#pragma unroll
        for (int xq = 0; xq < 4; ++xq) {
          c1[0][y1][x0 + 1 + xq] = fmaxf(a0[xq], 0.f);
          c1[1][y1][x0 + 1 + xq] = fmaxf(a1[xq], 0.f);
        }
      }
    }
    __syncthreads();
    if (t < 192) {
#pragma unroll
      for (int cc = 0; cc < 2; ++cc) {
#pragma unroll
        for (int ky = 0; ky < 3; ++ky) {
          float v[6];
#pragma unroll
          for (int i = 0; i < 6; ++i) v[i] = c1[cc][y1 + ky][x0 + i];
          const float* wr = &w2s[(2 * pc + cc) * 9 + ky * 3];
#pragma unroll
          for (int xq = 0; xq < 4; ++xq)
            s2[xq] += v[xq] * wr[0] + v[xq + 1] * wr[1] + v[xq + 2] * wr[2];
        }
      }
    }
    __syncthreads();
  }
  if (t < 192) {
    f32x4 o = {s2[0], s2[1], s2[2], s2[3]};
    *(f32x4*)(xfp + ((size_t)d * NB + b) * ND + (gy0 + y1) * 48 + x0) = o;
  }
}

// Reduce conv partials over d + bias + relu.
__global__ __launch_bounds__(256) void k_bias_relu(
    const float* __restrict__ xfp, const float* __restrict__ c2b, float* __restrict__ xf) {
  const size_t i = (size_t)blockIdx.x * 256 + threadIdx.x;
  float s = c2b[0];
#pragma unroll
  for (int d = 0; d < NL; ++d) s += xfp[(size_t)d * (NB * ND) + i];
  xf[i] = fmaxf(s, 0.f);
}

// Gating: logits, argmax (top-1, gate=1.0), counts, row compaction, aux loss.
__global__ __launch_bounds__(256) void k_gate(
    const float* __restrict__ xf,
    const float* __restrict__ g0, const float* __restrict__ g1, const float* __restrict__ g2,
    float* __restrict__ aux, int* __restrict__ cnt, int* __restrict__ rows) {
  const int p = blockIdx.x, t = threadIdx.x;
  const float* __restrict__ g = (p == 0) ? g0 : ((p == 1) ? g1 : g2);
  __shared__ float lg[64][4];
  __shared__ int lidx[64];
  __shared__ int lcnt[4];
  if (t < 4) lcnt[t] = 0;
  const int wv = t >> 6, l = t & 63;
  for (int b0 = 0; b0 < 64; b0 += 4) {
    int bb = b0 + wv;
    f32x4 acc = {0.f, 0.f, 0.f, 0.f};
    const float* xr = xf + (size_t)bb * ND + l * 36;
    const float* gr = g + (size_t)l * 36 * 4;
#pragma unroll
    for (int i4 = 0; i4 < 9; ++i4) {
      f32x4 xv = *(const f32x4*)(xr + i4 * 4);
#pragma unroll
      for (int qq = 0; qq < 4; ++qq) {
        f32x4 gv = *(const f32x4*)(gr + (i4 * 4 + qq) * 4);
        acc += xv[qq] * gv;
      }
    }
#pragma unroll
    for (int e = 0; e < 4; ++e) {
      float pv = acc[e];
#pragma unroll
      for (int off = 32; off > 0; off >>= 1) pv += __shfl_down(pv, off);
      if (l == 0) lg[bb][e] = pv;
    }
  }
  __syncthreads();
  if (t < 64) {
    float best = lg[t][0];
    int bi = 0;
#pragma unroll
    for (int e = 1; e < 4; ++e)
      if (lg[t][e] > best) { best = lg[t][e]; bi = e; }
    lidx[t] = bi;
    atomicAdd(&lcnt[bi], 1);
  }
  __syncthreads();
  if (t == 0) {
    int ofs[4]; int run = 0;
#pragma unroll
    for (int e = 0; e < 4; ++e) { ofs[e] = run; run += lcnt[e]; cnt[p * 4 + e] = lcnt[e]; }
    for (int b = 0; b < 64; ++b) { int e = lidx[b]; rows[p * 64 + ofs[e]++] = b; }
    float var = 0.f;
#pragma unroll
    for (int e = 0; e < 4; ++e) { float dd = (float)lcnt[e] - 16.f; var += dd * dd; }
    var *= (1.f / 3.f);
    aux[p] = 0.02f * var / (256.f + 1e-10f);
  }
}

// Compact xf rows into expert order + fp32->bf16: Xb[slot] = bf16(xf[rows[slot]]).
__global__ __launch_bounds__(256) void k_gather(
    const float* __restrict__ xf, const int* __restrict__ rows, u16* __restrict__ Xb) {
  const int slot = blockIdx.x, t = threadIdx.x;
  const int r = rows[slot];
  const f32x4* src = (const f32x4*)(xf + (size_t)r * ND);
  u16x4* dst = (u16x4*)(Xb + (size_t)slot * ND);
  for (int i = t; i < ND / 4; i += 256) {
    f32x4 v = src[i];
    u16x4 o;
#pragma unroll
    for (int q = 0; q < 4; ++q) o[q] = f2bf(v[q]);
    dst[i] = o;
  }
}

// MFMA expert GEMM v6 (frozen): 256-col weight tiles, 1KB contiguous staging,
// ring-2 LDS, counted vmcnt. 16 rows x 256 cols x KL=288 per block.
template <int K, int N, int KS>
__global__ __launch_bounds__(256) void k_moe_mfma(
    const u16* __restrict__ Xb,
    const float* __restrict__ wt, const float* __restrict__ wa, const float* __restrict__ wq,
    const int* __restrict__ cnt, float* __restrict__ P) {
  constexpr int KL = K / KS;      // 288
  constexpr int NT = KL / 32;     // 9
  const int tile = blockIdx.x;    // 256-col tile
  const int ks = blockIdx.y;
  const int pe = blockIdx.z >> 2, ch = blockIdx.z & 3;
  const int p = pe >> 2, e = pe & 3;
  const int c = cnt[p * 4 + e];
  const int rstart = ch * 16;
  if (rstart >= c) return;
  const int nrows = min(16, c - rstart);
  int pref = 0;
  for (int e2 = 0; e2 < e; ++e2) pref += cnt[p * 4 + e2];
  const int slot0 = p * 64 + pref + rstart;
  const float* __restrict__ W = (p == 0) ? wt : ((p == 1) ? wa : wq);
  __shared__ float wb[2][32 * 260 + 24];   // rows at k*260 + ((k>>3)&3)*8
  const int t = threadIdx.x;
  const int w = t >> 6, l = t & 63;
  const int l15 = l & 15, l4 = l >> 4;

  int ar = slot0 + l15; if (ar > 191) ar = 191;
  const u16* Ag = Xb + (size_t)ar * K + ks * KL + l4 * 8;
  bf16x8 areg[NT];
#pragma unroll
  for (int kt = 0; kt < NT; ++kt) areg[kt] = *(const bf16x8*)(Ag + kt * 32);

  const float* Wg = W + (size_t)e * K * N + (size_t)(ks * KL) * N + tile * 256;
#define STAGE(BUF, KT)                                                        \
  { _Pragma("unroll")                                                         \
    for (int j = 0; j < 8; ++j)                                               \
      gl_lds16(Wg + (size_t)((KT) * 32 + w * 8 + j) * N + l * 4,              \
               &wb[BUF][(w * 8 + j) * 260 + w * 8]); }

  f32x4 acc[4] = {};

#define CONSUME(KT)                                                           \
  { const float* ww = &wb[(KT) & 1][0];                                       \
    const int kb = l4 * 8 * 260 + l4 * 8 + w * 64 + l15;                      \
    _Pragma("unroll")                                                         \
    for (int i = 0; i < 4; ++i) {                                             \
      bf16x8 bfr;                                                             \
      _Pragma("unroll")                                                       \
      for (int j = 0; j < 8; ++j) bfr[j] = (__bf16)ww[kb + j * 260 + i * 16]; \
      acc[i] = __builtin_amdgcn_mfma_f32_16x16x32_bf16(areg[KT], bfr, acc[i], 0, 0, 0); \
    } }

  STAGE(0, 0);
  STAGE(1, 1);
#pragma unroll
  for (int kt = 0; kt < NT; ++kt) {
    if (kt < NT - 1) { asm volatile("s_waitcnt vmcnt(8)" ::: "memory"); }
    else             { asm volatile("s_waitcnt vmcnt(0)" ::: "memory"); }
    __syncthreads();
    CONSUME(kt);
    __syncthreads();
    if (kt + 2 < NT) STAGE(kt & 1, kt + 2);
  }
#undef STAGE
#undef CONSUME

  const size_t pbase = (size_t)ks * 192 * N;
#pragma unroll
  for (int i = 0; i < 4; ++i) {
    const int n = tile * 256 + w * 64 + i * 16 + l15;
#pragma unroll
    for (int r = 0; r < 4; ++r) {
      const int m = l4 * 4 + r;
      if (m < nrows) P[pbase + (size_t)(slot0 + m) * N + n] = acc[i][r];
    }
  }
}

// Reduce phase-A partials: Hb[slot][j] = bf16(relu(sum_ks P + b1[e])).
__global__ __launch_bounds__(256) void k_red1(
    const float* __restrict__ P,
    const float* __restrict__ b1t, const float* __restrict__ b1a, const float* __restrict__ b1q,
    const int* __restrict__ cnt, u16* __restrict__ Hb) {
  const int slot = blockIdx.y;
  const int p = slot >> 6, pos = slot & 63;
  int e = 0, run = cnt[p * 4];
  while (pos >= run && e < 3) { ++e; run += cnt[p * 4 + e]; }
  const float* __restrict__ b1 = (p == 0) ? b1t : ((p == 1) ? b1a : b1q);
  const int j0 = blockIdx.x * 1024 + threadIdx.x * 4;
  if (j0 >= NH) return;
  f32x4 s = *(const f32x4*)(b1 + (size_t)e * NH + j0);
#pragma unroll
  for (int ks = 0; ks < 8; ++ks)
    s += *(const f32x4*)(P + ((size_t)ks * 192 + slot) * NH + j0);
  u16x4 o;
#pragma unroll
  for (int q = 0; q < 4; ++q) o[q] = f2bf(fmaxf(s[q], 0.f));
  *(u16x4*)(Hb + (size_t)slot * NH + j0) = o;
}

// Reduce phase-B partials + scatter: Y[p*64+rows[slot]][j] = sum_ks P + b2[e].
__global__ __launch_bounds__(256) void k_red2(
    const float* __restrict__ P,
    const float* __restrict__ b2t, const float* __restrict__ b2a, const float* __restrict__ b2q,
    const int* __restrict__ cnt, const int* __restrict__ rows, float* __restrict__ Y) {
  const int slot = blockIdx.y;
  const int p = slot >> 6, pos = slot & 63;
  int e = 0, run = cnt[p * 4];
  while (pos >= run && e < 3) { ++e; run += cnt[p * 4 + e]; }
  const float* __restrict__ b2 = (p == 0) ? b2t : ((p == 1) ? b2a : b2q);
  const int b = rows[slot];
  const int t = threadIdx.x;
  if (t >= 192) return;
  const int j0 = blockIdx.x * 768 + t * 4;
  f32x4 s = *(const f32x4*)(b2 + (size_t)e * ND + j0);
#pragma unroll
  for (int ks = 0; ks < 16; ++ks)
    s += *(const f32x4*)(P + ((size_t)ks * 192 + slot) * ND + j0);
  *(f32x4*)(Y + (size_t)(p * 64 + b) * ND + j0) = s;
}

// out = in*in*quad + in*transform + add, convert to bf16 for encoder GEMM.
__global__ __launch_bounds__(256) void k_combine(
    const float* __restrict__ in, const float* __restrict__ Y, u16* __restrict__ ofb) {
  const size_t i = (size_t)blockIdx.x * 256 + threadIdx.x;
  const size_t e0 = i * 4;
  const int row = (int)(e0 / ND);
  const int d = (int)(e0 - (size_t)row * ND);
  const int b = row / NL;
  f32x4 v = *(const f32x4*)(in + e0);
  const size_t yb = (size_t)b * ND + d;
  f32x4 tt = *(const f32x4*)(Y + yb);
  f32x4 aa = *(const f32x4*)(Y + (size_t)64 * ND + yb);
  f32x4 qq = *(const f32x4*)(Y + (size_t)128 * ND + yb);
  u16x4 o;
#pragma unroll
  for (int q = 0; q < 4; ++q) {
    float f = v[q] * v[q] * qq[q] + v[q] * tt[q] + aa[q];
    o[q] = f2bf(f);
  }
  *(u16x4*)(ofb + e0) = o;
}

// Transpose + fp32->bf16: W^T so GEMM B-operand is [N][K] row-major.
__global__ __launch_bounds__(256) void k_wt(
    const float* __restrict__ encw, const float* __restrict__ decw,
    u16* __restrict__ encb, u16* __restrict__ decb) {
  __shared__ float tl[32][33];
  const float* __restrict__ src = blockIdx.z ? decw : encw;
  u16* __restrict__ dst = blockIdx.z ? decb : encb;
  const int k0 = blockIdx.x * 32, n0 = blockIdx.y * 32;
  const int tx = threadIdx.x & 31, ty = threadIdx.x >> 5;
  for (int r = ty; r < 32; r += 8) tl[r][tx] = src[(size_t)(k0 + r) * ND + n0 + tx];
  __syncthreads();
  for (int r = ty; r < 32; r += 8) dst[(size_t)(n0 + r) * ND + k0 + tx] = f2bf(tl[tx][r]);
}

// 64x128 bf16 MFMA GEMM (360 blocks), A[M][K] row-major, Bt[N][K] row-major.
template <int MODE>
__global__ __launch_bounds__(256) void k_gemm(
    const u16* __restrict__ A, const u16* __restrict__ Bt,
    const float* __restrict__ bias, void* __restrict__ outp,
    const float* __restrict__ aux) {
  __shared__ u16 As[64 * 32];
  __shared__ u16 Bs[128 * 32];
  const int t = threadIdx.x;
  const int bm = blockIdx.x, bn = blockIdx.y;
  const int lane = t & 63;
  const int wr = (t >> 7) & 1, wc = (t >> 6) & 1;
  const int l15 = lane & 15, l4 = lane >> 4;
  f32x4 acc[2][4] = {};
  const int r0 = t >> 2, kc0 = (t & 3) * 8;
  const int r1 = (t + 256) >> 2, kc1 = ((t + 256) & 3) * 8;
  const size_t baseA = (size_t)(bm * 64) * ND;
  const size_t baseB = (size_t)(bn * 128) * ND;
  for (int k0 = 0; k0 < ND; k0 += 32) {
    *(u32x4*)(As + t * 8) = *(const u32x4*)(A + baseA + (size_t)r0 * ND + k0 + kc0);
    *(u32x4*)(Bs + t * 8) = *(const u32x4*)(Bt + baseB + (size_t)r0 * ND + k0 + kc0);
    *(u32x4*)(Bs + (t + 256) * 8) = *(const u32x4*)(Bt + baseB + (size_t)r1 * ND + k0 + kc1);
    __syncthreads();
    bf16x8 af[2], bfr[4];
#pragma unroll
    for (int i = 0; i < 2; ++i)
      af[i] = *(const bf16x8*)(As + (wr * 32 + i * 16 + l15) * 32 + l4 * 8);
#pragma unroll
    for (int i = 0; i < 4; ++i)
      bfr[i] = *(const bf16x8*)(Bs + (wc * 64 + i * 16 + l15) * 32 + l4 * 8);
#pragma unroll
    for (int mi = 0; mi < 2; ++mi)
#pragma unroll
      for (int ni = 0; ni < 4; ++ni)
        acc[mi][ni] = __builtin_amdgcn_mfma_f32_16x16x32_bf16(af[mi], bfr[ni], acc[mi][ni], 0, 0, 0);
    __syncthreads();
  }
  const int colbase = bn * 128 + wc * 64;
  const int rowbase = bm * 64 + wr * 32;
#pragma unroll
  for (int mi = 0; mi < 2; ++mi) {
#pragma unroll
    for (int ni = 0; ni < 4; ++ni) {
      const int colg = colbase + ni * 16 + l15;
      const float bv = bias[colg];
#pragma unroll
      for (int r = 0; r < 4; ++r) {
        const int rowg = rowbase + mi * 16 + l4 * 4 + r;
        float v = acc[mi][ni][r] + bv;
        if (MODE == 0) {
          ((u16*)outp)[(size_t)rowg * ND + colg] = f2bf(fmaxf(v, 0.f));
        } else {
          ((float*)outp)[(size_t)rowg * ND + colg] = 1.f / (1.f + __expf(-v));
        }
      }
    }
  }
  if (MODE == 1 && bm == 0 && bn == 0 && t == 0)
    ((float*)outp)[(size_t)NM * ND] = aux[0] + aux[1] + aux[2];
}

extern "C" void kernel_launch(void* const* d_in, const int* in_sizes, int n_in,
                              void* d_out, int out_size, void* d_ws, size_t ws_size,
                              hipStream_t stream) {
  (void)in_sizes; (void)n_in; (void)out_size; (void)ws_size;
  const float* input   = (const float*)d_in[0];
  const float* conv1_w = (const float*)d_in[1];
  const float* conv1_b = (const float*)d_in[2];
  const float* conv2_w = (const float*)d_in[3];
  const float* conv2_b = (const float*)d_in[4];
  const float* enc_w   = (const float*)d_in[5];
  const float* enc_b   = (const float*)d_in[6];
  const float* dec_w   = (const float*)d_in[7];
  const float* dec_b   = (const float*)d_in[8];
  const float* gate_t = (const float*)d_in[9];
  const float* w1_t   = (const float*)d_in[10];
  const float* b1_t   = (const float*)d_in[11];
  const float* w2_t   = (const float*)d_in[12];
  const float* b2_t   = (const float*)d_in[13];
  const float* gate_a = (const float*)d_in[14];
  const float* w1_a   = (const float*)d_in[15];
  const float* b1_a   = (const float*)d_in[16];
  const float* w2_a   = (const float*)d_in[17];
  const float* b2_a   = (const float*)d_in[18];
  const float* gate_q = (const float*)d_in[19];
  const float* w1_q   = (const float*)d_in[20];
  const float* b1_q   = (const float*)d_in[21];
  const float* w2_q   = (const float*)d_in[22];
  const float* b2_q   = (const float*)d_in[23];

  float* ws = (float*)d_ws;
  float* xf     = ws + OFF_XF;
  u16*   Hb     = (u16*)(ws + OFF_H);
  float* Y      = ws + OFF_Y;
  float* aux    = ws + OFF_AUX;
  int*   cnt    = (int*)(ws + OFF_CNT);
  int*   rows   = (int*)(ws + OFF_ROWS);
  u16*   ofb    = (u16*)(ws + OFF_OFB);
  u16*   h1b    = (u16*)(ws + OFF_H1B);
  u16*   encwb  = (u16*)(ws + OFF_ENCWB);
  u16*   decwb  = (u16*)(ws + OFF_DECWB);
  u16*   Xcb    = (u16*)(ws + OFF_XC);
  float* P      = ws + OFF_P;

  // conv partials live in P-space (consumed by k_bias_relu before MoE writes P)
  k_conv<<<dim3(20, 64, 3), 256, 0, stream>>>(input, conv1_w, conv1_b, conv2_w, P);
  k_bias_relu<<<576, 256, 0, stream>>>(P, conv2_b, xf);
  k_wt<<<dim3(72, 72, 2), 256, 0, stream>>>(enc_w, dec_w, encwb, decwb);
  k_gate<<<3, 256, 0, stream>>>(xf, gate_t, gate_a, gate_q, aux, cnt, rows);
  k_gather<<<192, 256, 0, stream>>>(xf, rows, Xcb);
  // Phase A: Xcb(bf16, A-in-regs) @ w1(fp32, 1KB-chunk staging) -> P -> Hb(bf16)
  k_moe_mfma<ND, NH, 8><<<dim3(18, 8, 48), 256, 0, stream>>>(Xcb, w1_t, w1_a, w1_q, cnt, P);
  k_red1<<<dim3(5, 192), 256, 0, stream>>>(P, b1_t, b1_a, b1_q, cnt, Hb);
  // Phase B: Hb(bf16) @ w2 -> P -> Y (scattered, fp32)
  k_moe_mfma<NH, ND, 16><<<dim3(9, 16, 48), 256, 0, stream>>>(Hb, w2_t, w2_a, w2_q, cnt, P);
  k_red2<<<dim3(3, 192), 256, 0, stream>>>(P, b2_t, b2_a, b2_q, cnt, rows, Y);
  k_combine<<<2880, 256, 0, stream>>>(input, Y, ofb);
  k_gemm<0><<<dim3(20, 18), 256, 0, stream>>>(ofb, encwb, enc_b, (void*)h1b, aux);
  k_gemm<1><<<dim3(20, 18), 256, 0, stream>>>(h1b, decwb, dec_b, d_out, aux);
}